// Round 1
// baseline (529.825 us; speedup 1.0000x reference)
//
#include <hip/hip_runtime.h>

#define LEAKY 0.01f
#define BN_EPS 1e-5f

// ---------------- degree count ----------------
__global__ __launch_bounds__(256) void k_count(const int* __restrict__ dst,
                                               int* __restrict__ cnt, int e) {
  int i = blockIdx.x * 256 + threadIdx.x;
  if (i < e) atomicAdd(&cnt[dst[i]], 1);
}

__global__ __launch_bounds__(256) void k_dinv(const int* __restrict__ cnt,
                                              float* __restrict__ dinv, int n) {
  int i = blockIdx.x * 256 + threadIdx.x;
  if (i < n) dinv[i] = rsqrtf((float)(cnt[i] + 1));  // +1 self-loop; deg>=1 always
}

// ---------------- exclusive scan (3-kernel) ----------------
// scanA: 256 threads x 4 elems = 1024 per block
__global__ __launch_bounds__(256) void k_scanA(const int* __restrict__ in,
                                               int* __restrict__ out,
                                               int* __restrict__ bsums, int n) {
  __shared__ int sdata[256];
  int t = threadIdx.x;
  int base = blockIdx.x * 1024 + t * 4;
  int v[4];
#pragma unroll
  for (int j = 0; j < 4; j++) v[j] = (base + j < n) ? in[base + j] : 0;
  int tsum = v[0] + v[1] + v[2] + v[3];
  sdata[t] = tsum;
  __syncthreads();
  for (int off = 1; off < 256; off <<= 1) {
    int x = (t >= off) ? sdata[t - off] : 0;
    __syncthreads();
    sdata[t] += x;
    __syncthreads();
  }
  int run = sdata[t] - tsum;  // exclusive prefix of this thread
#pragma unroll
  for (int j = 0; j < 4; j++) {
    if (base + j < n) out[base + j] = run;
    run += v[j];
  }
  if (t == 255) bsums[blockIdx.x] = sdata[255];
}

__global__ __launch_bounds__(256) void k_scanB(int* __restrict__ bsums, int nb) {
  __shared__ int sdata[256];
  int t = threadIdx.x;
  int v = (t < nb) ? bsums[t] : 0;
  sdata[t] = v;
  __syncthreads();
  for (int off = 1; off < 256; off <<= 1) {
    int x = (t >= off) ? sdata[t - off] : 0;
    __syncthreads();
    sdata[t] += x;
    __syncthreads();
  }
  if (t < nb) bsums[t] = sdata[t] - v;  // exclusive
}

__global__ __launch_bounds__(256) void k_scanC(int* __restrict__ out,
                                               const int* __restrict__ bsums, int n) {
  int i = blockIdx.x * 256 + threadIdx.x;
  if (i < n) out[i] += bsums[i >> 10];
}

// ---------------- CSR scatter ----------------
__global__ __launch_bounds__(256) void k_scatter(const int* __restrict__ src,
                                                 const int* __restrict__ dst,
                                                 const int* __restrict__ off,
                                                 int* __restrict__ cur,
                                                 int* __restrict__ csr, int e) {
  int i = blockIdx.x * 256 + threadIdx.x;
  if (i < e) {
    int d = dst[i];
    int p = off[d] + atomicAdd(&cur[d], 1);
    csr[p] = src[i];
  }
}

// ---------------- 64x64 GEMM: Y[n,64] = X[n,64] @ W[64,64], opt fused BN+LeakyReLU on X
template <bool BN>
__global__ __launch_bounds__(256) void k_gemm(const float* __restrict__ X,
                                              const float* __restrict__ W,
                                              float* __restrict__ Y, int n,
                                              const float* __restrict__ bnp,
                                              const float* __restrict__ gamma,
                                              const float* __restrict__ beta) {
  __shared__ float Ws[64][68];  // 68: rows 16B-aligned, banks spread
  __shared__ float Xs[64][65];
  int t = threadIdx.x;
  for (int j = t; j < 4096; j += 256) Ws[j >> 6][j & 63] = W[j];
  int rowbase = blockIdx.x * 64;
  for (int j = t; j < 4096; j += 256) {
    int r = j >> 6, c = j & 63;
    int gr = rowbase + r;
    float v = (gr < n) ? X[(size_t)gr * 64 + c] : 0.f;
    if (BN) {
      v = gamma[c] * (v - bnp[c]) * bnp[64 + c] + beta[c];
      v = (v >= 0.f) ? v : LEAKY * v;
    }
    Xs[r][c] = v;
  }
  __syncthreads();
  int r = t >> 2;       // 0..63
  int cq = t & 3;       // 16-col quarter
  float acc[16];
#pragma unroll
  for (int j = 0; j < 16; j++) acc[j] = 0.f;
#pragma unroll 4
  for (int k = 0; k < 64; k++) {
    float xv = Xs[r][k];
#pragma unroll
    for (int j = 0; j < 16; j++) acc[j] += xv * Ws[k][cq * 16 + j];
  }
  int gr = rowbase + r;
  if (gr < n) {
#pragma unroll
    for (int j = 0; j < 16; j++) Y[(size_t)gr * 64 + cq * 16 + j] = acc[j];
  }
}

// ---------------- gather aggregation: O[i] = sum_{e: dst=i} H[src]*dinv_i*dinv_src + H[i]*dinv_i^2 + b
__global__ __launch_bounds__(256) void k_agg(const float* __restrict__ H,
                                             float* __restrict__ O,
                                             const int* __restrict__ off,
                                             const int* __restrict__ cnt,
                                             const int* __restrict__ csr,
                                             const float* __restrict__ dinv,
                                             const float* __restrict__ bias, int n) {
  int wave = (blockIdx.x * 256 + threadIdx.x) >> 6;
  int lane = threadIdx.x & 63;
  if (wave >= n) return;
  int i = wave;
  float di = dinv[i];
  float acc = H[(size_t)i * 64 + lane] * (di * di);
  int s0 = off[i], s1 = s0 + cnt[i];
  int j = s0;
  for (; j + 1 < s1; j += 2) {
    int sa = csr[j], sb = csr[j + 1];
    float wa = di * dinv[sa], wb = di * dinv[sb];
    acc += H[(size_t)sa * 64 + lane] * wa;
    acc += H[(size_t)sb * 64 + lane] * wb;
  }
  if (j < s1) {
    int sa = csr[j];
    acc += H[(size_t)sa * 64 + lane] * (di * dinv[sa]);
  }
  O[(size_t)i * 64 + lane] = acc + bias[lane];
}

// ---------------- BN batch stats (double atomics) ----------------
__global__ __launch_bounds__(256) void k_bnstats(const float* __restrict__ H,
                                                 double* __restrict__ st, int n) {
  __shared__ double ls[4][64], lss[4][64];
  int lane = threadIdx.x & 63;
  int w = threadIdx.x >> 6;
  int rw = blockIdx.x * 4 + w;
  int nrw = gridDim.x * 4;
  double s = 0.0, ss = 0.0;
  for (int r = rw; r < n; r += nrw) {
    float v = H[(size_t)r * 64 + lane];
    s += v;
    ss += (double)v * v;
  }
  ls[w][lane] = s;
  lss[w][lane] = ss;
  __syncthreads();
  if (w == 0) {
    double a = ls[0][lane] + ls[1][lane] + ls[2][lane] + ls[3][lane];
    double b = lss[0][lane] + lss[1][lane] + lss[2][lane] + lss[3][lane];
    atomicAdd(&st[lane], a);
    atomicAdd(&st[64 + lane], b);
  }
}

__global__ __launch_bounds__(64) void k_bnfin(const double* __restrict__ st,
                                              float* __restrict__ bnp, int n) {
  int c = threadIdx.x;
  double mu = st[c] / n;
  double var = st[64 + c] / n - mu * mu;
  bnp[c] = (float)mu;
  bnp[64 + c] = (float)(1.0 / sqrt(var + (double)BN_EPS));
}

extern "C" void kernel_launch(void* const* d_in, const int* in_sizes, int n_in,
                              void* d_out, int out_size, void* d_ws, size_t ws_size,
                              hipStream_t stream) {
  const float* x     = (const float*)d_in[0];
  const int*   ei    = (const int*)d_in[1];
  const float* W1    = (const float*)d_in[2];
  const float* b1    = (const float*)d_in[3];
  const float* gamma = (const float*)d_in[4];
  const float* beta  = (const float*)d_in[5];
  const float* W2    = (const float*)d_in[6];
  const float* b2    = (const float*)d_in[7];
  float* out = (float*)d_out;

  int n = in_sizes[0] / 64;
  int e = in_sizes[1] / 2;
  const int* srcv = ei;
  const int* dstv = ei + e;

  char* ws = (char*)d_ws;
  size_t p = 0;
  auto alloc = [&](size_t bytes) {
    void* r = ws + p;
    p += (bytes + 255) & ~(size_t)255;
    return r;
  };
  int*    counts = (int*)alloc((size_t)n * 4);
  int*    off    = (int*)alloc((size_t)n * 4);
  int*    bsums  = (int*)alloc(1024);
  float*  dinv   = (float*)alloc((size_t)n * 4);
  int*    csr    = (int*)alloc((size_t)e * 4);
  double* st     = (double*)alloc(128 * 8);
  float*  bnp    = (float*)alloc(128 * 4);
  float*  A      = (float*)alloc((size_t)n * 64 * 4);
  float*  B      = (float*)alloc((size_t)n * 64 * 4);

  hipMemsetAsync(counts, 0, (size_t)n * 4, stream);
  hipMemsetAsync(st, 0, 128 * 8, stream);

  int gE = (e + 255) / 256;
  int gN = (n + 255) / 256;
  int nb = (n + 1023) / 1024;
  int gG = (n + 63) / 64;
  int gAgg = (n + 3) / 4;

  k_count<<<gE, 256, 0, stream>>>(dstv, counts, e);
  k_dinv<<<gN, 256, 0, stream>>>(counts, dinv, n);
  k_scanA<<<nb, 256, 0, stream>>>(counts, off, bsums, n);
  k_scanB<<<1, 256, 0, stream>>>(bsums, nb);
  k_scanC<<<gN, 256, 0, stream>>>(off, bsums, n);
  hipMemsetAsync(counts, 0, (size_t)n * 4, stream);
  k_scatter<<<gE, 256, 0, stream>>>(srcv, dstv, off, counts, csr, e);

  k_gemm<false><<<gG, 256, 0, stream>>>(x, W1, A, n, nullptr, nullptr, nullptr);
  k_agg<<<gAgg, 256, 0, stream>>>(A, B, off, counts, csr, dinv, b1, n);
  k_bnstats<<<256, 256, 0, stream>>>(B, st, n);
  k_bnfin<<<1, 64, 0, stream>>>(st, bnp, n);
  k_gemm<true><<<gG, 256, 0, stream>>>(B, W2, A, n, bnp, gamma, beta);
  k_agg<<<gAgg, 256, 0, stream>>>(A, out, off, counts, csr, dinv, b2, n);
}